// Round 10
// baseline (96.760 us; speedup 1.0000x reference)
//
#include <hip/hip_runtime.h>
#include <math.h>

#define NBINS 15
#define CROWS 16                      // rows per wave-chunk
#define F4C   (CROWS * 25)            // 400 float4 per chunk (6.4 KB)
#define BLOCK 256
#define WPB   (BLOCK / 64)            // 4 waves per block

__device__ __forceinline__ void compute_chunk(
    const float4* __restrict__ buf, int r, int q, long long rbase, int labCur,
    float scale, int N, float* s_cnt, float* s_conf, float* s_acc)
{
    if (rbase + r >= N) return;
    const float4* rowp = buf + r * 25;
    const int nf = (q == 0) ? 7 : 6;
    const int fb = (q == 0) ? 0 : (1 + q * 6);   // f4 ranges: 0-6,7-12,13-18,19-24

    float4 v[7];
#pragma unroll
    for (int j = 0; j < 7; ++j)
        if (j < nf) v[j] = rowp[fb + j];          // ds_read_b128, static idx

    float m = -INFINITY; int mi = 0;
#pragma unroll
    for (int j = 0; j < 7; ++j) if (j < nf) {
        const int cb = (fb + j) * 4;
        float4 w = v[j];
        w.x *= scale; w.y *= scale; w.z *= scale; w.w *= scale;
        v[j] = w;
        if (w.x > m) { m = w.x; mi = cb;     }
        if (w.y > m) { m = w.y; mi = cb + 1; }
        if (w.z > m) { m = w.z; mi = cb + 2; }
        if (w.w > m) { m = w.w; mi = cb + 3; }
    }
#pragma unroll
    for (int off = 1; off <= 2; off <<= 1) {
        const float om  = __shfl_xor(m, off);
        const int   omi = __shfl_xor(mi, off);
        if (om > m || (om == m && omi < mi)) { m = om; mi = omi; }
    }

    float e = 0.f;
#pragma unroll
    for (int j = 0; j < 7; ++j) if (j < nf) {
        const float4 w = v[j];
        e += __expf(w.x - m) + __expf(w.y - m)
           + __expf(w.z - m) + __expf(w.w - m);
    }
    e += __shfl_xor(e, 1);
    e += __shfl_xor(e, 2);

    if (q == 0) {
        const float conf = 1.0f / e;
        const float acc  = (mi == labCur) ? 1.0f : 0.0f;
        int jc = 0;
#pragma unroll
        for (int i = 0; i <= NBINS; ++i) {
            const float b = (float)i * (1.0f / 15.0f);
            jc += (b < conf) ? 1 : 0;
        }
        int bin = jc - 1;
        bin = bin < 0 ? 0 : (bin > NBINS - 1 ? NBINS - 1 : bin);
        atomicAdd(&s_cnt[bin],  1.0f);
        atomicAdd(&s_conf[bin], conf);
        atomicAdd(&s_acc[bin],  acc);
    }
}

// gbins layout in d_ws: [0..14]=counts, [15..29]=sum_conf, [30..44]=sum_acc
__global__ __launch_bounds__(BLOCK, 3) void ece_main(const float* __restrict__ logits,
                                                     const int* __restrict__ labels,
                                                     const int* __restrict__ t_opt,
                                                     float* __restrict__ gbins,
                                                     int N) {
    __shared__ float4 s_tile[WPB][2][F4C];       // wave-private double buffers, 51.2 KB
    __shared__ float s_cnt[NBINS], s_conf[NBINS], s_acc[NBINS];

    const int tid  = threadIdx.x;
    const int lane = tid & 63;
    const int wv   = tid >> 6;
    const int r    = lane >> 2;      // row in chunk 0..15
    const int q    = lane & 3;       // quarter of row

    if (tid < NBINS) { s_cnt[tid] = 0.f; s_conf[tid] = 0.f; s_acc[tid] = 0.f; }
    __syncthreads();                 // hist init visible; ONLY pre-loop barrier

    const int tt = t_opt[0];
    float scale = (tt != 0) ? (1.0f / (float)tt) : 1.0f;
    asm volatile("" :: "v"(scale));  // materialize before staging (keep vmcnt stream clean)

    const float4* __restrict__ lg4 = (const float4*)logits;
    const int limF4   = N * 25 - 1;  // 25e6 fits int
    const int nChunks = (N + CROWS - 1) / CROWS;
    const int stride  = gridDim.x * WPB;

    // named staging registers (NO arrays/lambdas -> no scratch demotion)
    float4 sA0, sA1, sA2, sA3, sA4, sA5, sA6;  int labsA = 0;
    float4 sB0, sB1, sB2, sB3, sB4, sB5, sB6;  int labsB = 0;

#define CLK(k) ((k) < limF4 ? (k) : limF4)
#define ISSUE(P, cc) do {                                                     \
    const int b_ = (cc) * F4C + lane;                                         \
    P##0 = lg4[CLK(b_)];       P##1 = lg4[CLK(b_ + 64)];                      \
    P##2 = lg4[CLK(b_ + 128)]; P##3 = lg4[CLK(b_ + 192)];                     \
    P##4 = lg4[CLK(b_ + 256)]; P##5 = lg4[CLK(b_ + 320)];                     \
    if (lane < 16) P##6 = lg4[CLK(b_ + 384)];                                 \
    if (q == 0) { const int rr_ = (cc) * CROWS + r;                           \
                  lab##P = labels[rr_ < N ? rr_ : N - 1]; }                   \
} while (0)
// each ISSUE = exactly 8 vmem loads per wave (6 full + 2 exec-masked)
// NOTE: lab##P with P=sA pastes to labsA (declared above).

#define DSW(P, b) do {                                                        \
    float4* d_ = &s_tile[wv][b][lane];                                        \
    d_[0]   = P##0; d_[64]  = P##1; d_[128] = P##2;                           \
    d_[192] = P##3; d_[256] = P##4; d_[320] = P##5;                           \
    if (lane < 16) d_[384] = P##6;                                            \
} while (0)

#define VMW8  asm volatile("s_waitcnt vmcnt(8)" ::: "memory")
#define VMW0  asm volatile("s_waitcnt vmcnt(0)" ::: "memory")
#define LGKM0 asm volatile("s_waitcnt lgkmcnt(0)" ::: "memory")
#define SBR   __builtin_amdgcn_sched_barrier(0)

    int  c     = blockIdx.x * WPB + wv;   // this wave's first chunk
    bool vCur  = (c < nChunks);
    bool vNext = (c + stride < nChunks);
    int  cur   = 0;

    if (vCur)  ISSUE(sA, c);
    if (vNext) ISSUE(sB, c + stride);
    if (vCur) {
        if (vNext) VMW8; else VMW0;       // set A landed; B stays in flight
        SBR;
        DSW(sA, 0);
        LGKM0; SBR;                       // same-wave RAW: writes complete before reads
    }

    if (vCur) for (;;) {
        {   // phase A: compute chunk c (set A -> buf cur); set B in flight
            const int  cn2 = c + 2 * stride;
            const bool v2  = cn2 < nChunks;
            const int  labCur = labsA;            // copy before re-issue clobbers
            if (v2) ISSUE(sA, cn2);
            compute_chunk(&s_tile[wv][cur][0], r, q, (long long)c * CROWS,
                          labCur, scale, N, s_cnt, s_conf, s_acc);
            if (vNext) {
                if (v2) VMW8; else VMW0;          // set B landed
                SBR;
                DSW(sB, cur ^ 1);
                LGKM0; SBR;
            }
            vCur = vNext; vNext = v2; c += stride; cur ^= 1;
            if (!vCur) break;
        }
        {   // phase B: roles swapped
            const int  cn2 = c + 2 * stride;
            const bool v2  = cn2 < nChunks;
            const int  labCur = labsB;
            if (v2) ISSUE(sB, cn2);
            compute_chunk(&s_tile[wv][cur][0], r, q, (long long)c * CROWS,
                          labCur, scale, N, s_cnt, s_conf, s_acc);
            if (vNext) {
                if (v2) VMW8; else VMW0;          // set A landed
                SBR;
                DSW(sA, cur ^ 1);
                LGKM0; SBR;
            }
            vCur = vNext; vNext = v2; c += stride; cur ^= 1;
            if (!vCur) break;
        }
    }

    VMW0;                 // no loads outstanding at endpgm
    __syncthreads();      // all histogram atomics done before flush
    if (tid < NBINS) {
        atomicAdd(&gbins[tid],             s_cnt[tid]);
        atomicAdd(&gbins[NBINS + tid],     s_conf[tid]);
        atomicAdd(&gbins[2 * NBINS + tid], s_acc[tid]);
    }
#undef CLK
#undef ISSUE
#undef DSW
#undef VMW8
#undef VMW0
#undef LGKM0
#undef SBR
}

__global__ void ece_final(const float* __restrict__ gbins,
                          float* __restrict__ out, int N) {
    if (threadIdx.x == 0 && blockIdx.x == 0) {
        float ece = 0.f;
        for (int b = 0; b < NBINS; ++b) {
            const float c = gbins[b];
            if (c > 0.f) {
                const float avg_conf = gbins[NBINS + b] / c;
                const float avg_acc  = gbins[2 * NBINS + b] / c;
                ece += fabsf(avg_conf - avg_acc) * (c / (float)N);
            }
        }
        out[0] = ece;
    }
}

extern "C" void kernel_launch(void* const* d_in, const int* in_sizes, int n_in,
                              void* d_out, int out_size, void* d_ws, size_t ws_size,
                              hipStream_t stream) {
    const float* logits = (const float*)d_in[0];
    const int*   labels = (const int*)d_in[1];
    const int*   t_opt  = (const int*)d_in[2];
    float* out   = (float*)d_out;
    float* gbins = (float*)d_ws;

    const int N = in_sizes[1];               // 1,000,000 rows (C fixed at 100)

    hipMemsetAsync(gbins, 0, 3 * NBINS * sizeof(float), stream);

    const int nChunks = (N + CROWS - 1) / CROWS;
    int blocks = (nChunks + WPB - 1) / WPB;
    if (blocks > 768) blocks = 768;          // 3 blocks/CU x 256 CU, 12 free-running waves/CU
    ece_main<<<blocks, BLOCK, 0, stream>>>(logits, labels, t_opt, gbins, N);
    ece_final<<<1, 64, 0, stream>>>(gbins, out, N);
}

// Round 11
// 87.190 us; speedup vs baseline: 1.1098x; 1.1098x over previous
//
#include <hip/hip_runtime.h>
#include <math.h>

#define NBINS 15
#define CROWS 16                      // rows per wave-chunk
#define F4C   (CROWS * 25)            // 400 float4 per chunk (6.4 KB)
#define BLOCK 256
#define WPB   (BLOCK / 64)            // 4 waves per block

typedef float nat_f4 __attribute__((ext_vector_type(4)));   // nontemporal-loadable

__device__ __forceinline__ void compute_chunk(
    const float4* __restrict__ buf, int r, int q, long long rbase, int labCur,
    float scale, int N, float* s_cnt, float* s_conf, float* s_acc)
{
    if (rbase + r >= N) return;
    const float4* rowp = buf + r * 25;
    const int nf = (q == 0) ? 7 : 6;
    const int fb = (q == 0) ? 0 : (1 + q * 6);   // f4 ranges: 0-6,7-12,13-18,19-24

    float4 v[7];
#pragma unroll
    for (int j = 0; j < 7; ++j)
        if (j < nf) v[j] = rowp[fb + j];          // ds_read_b128, static idx

    float m = -INFINITY; int mi = 0;
#pragma unroll
    for (int j = 0; j < 7; ++j) if (j < nf) {
        const int cb = (fb + j) * 4;
        float4 w = v[j];
        w.x *= scale; w.y *= scale; w.z *= scale; w.w *= scale;
        v[j] = w;
        if (w.x > m) { m = w.x; mi = cb;     }
        if (w.y > m) { m = w.y; mi = cb + 1; }
        if (w.z > m) { m = w.z; mi = cb + 2; }
        if (w.w > m) { m = w.w; mi = cb + 3; }
    }
#pragma unroll
    for (int off = 1; off <= 2; off <<= 1) {
        const float om  = __shfl_xor(m, off);
        const int   omi = __shfl_xor(mi, off);
        if (om > m || (om == m && omi < mi)) { m = om; mi = omi; }
    }

    float e = 0.f;
#pragma unroll
    for (int j = 0; j < 7; ++j) if (j < nf) {
        const float4 w = v[j];
        e += __expf(w.x - m) + __expf(w.y - m)
           + __expf(w.z - m) + __expf(w.w - m);
    }
    e += __shfl_xor(e, 1);
    e += __shfl_xor(e, 2);

    if (q == 0) {
        const float conf = 1.0f / e;
        const float acc  = (mi == labCur) ? 1.0f : 0.0f;
        int jc = 0;
#pragma unroll
        for (int i = 0; i <= NBINS; ++i) {
            const float b = (float)i * (1.0f / 15.0f);
            jc += (b < conf) ? 1 : 0;
        }
        int bin = jc - 1;
        bin = bin < 0 ? 0 : (bin > NBINS - 1 ? NBINS - 1 : bin);
        atomicAdd(&s_cnt[bin],  1.0f);
        atomicAdd(&s_conf[bin], conf);
        atomicAdd(&s_acc[bin],  acc);
    }
}

// gbins layout in d_ws: [0..14]=counts, [15..29]=sum_conf, [30..44]=sum_acc
__global__ __launch_bounds__(BLOCK, 3) void ece_main(const float* __restrict__ logits,
                                                     const int* __restrict__ labels,
                                                     const int* __restrict__ t_opt,
                                                     float* __restrict__ gbins,
                                                     int N) {
    __shared__ float4 s_tile[WPB][2][F4C];       // wave-private double buffers, 51.2 KB
    __shared__ float s_cnt[NBINS], s_conf[NBINS], s_acc[NBINS];

    const int tid  = threadIdx.x;
    const int lane = tid & 63;
    const int wv   = tid >> 6;
    const int r    = lane >> 2;      // row in chunk 0..15
    const int q    = lane & 3;       // quarter of row

    if (tid < NBINS) { s_cnt[tid] = 0.f; s_conf[tid] = 0.f; s_acc[tid] = 0.f; }
    __syncthreads();                 // hist init visible; ONLY pre-loop barrier

    const int tt = t_opt[0];
    float scale = (tt != 0) ? (1.0f / (float)tt) : 1.0f;
    asm volatile("" :: "v"(scale));  // materialize before staging (keep vmcnt stream clean)

    const nat_f4* __restrict__ lg4 = (const nat_f4*)logits;
    const int limF4   = N * 25 - 1;  // 25e6 fits int
    const int nChunks = (N + CROWS - 1) / CROWS;
    const int stride  = gridDim.x * WPB;

    // named staging registers (NO arrays/lambdas -> no scratch demotion)
    nat_f4 sA0, sA1, sA2, sA3, sA4, sA5, sA6;  int labsA = 0;
    nat_f4 sB0, sB1, sB2, sB3, sB4, sB5, sB6;  int labsB = 0;

#define CLK(k) ((k) < limF4 ? (k) : limF4)
// NONTEMPORAL loads: nt flag -> no LLC allocation (single delta vs R10)
#define ISSUE(P, cc) do {                                                     \
    const int b_ = (cc) * F4C + lane;                                         \
    P##0 = __builtin_nontemporal_load(lg4 + CLK(b_));                         \
    P##1 = __builtin_nontemporal_load(lg4 + CLK(b_ + 64));                    \
    P##2 = __builtin_nontemporal_load(lg4 + CLK(b_ + 128));                   \
    P##3 = __builtin_nontemporal_load(lg4 + CLK(b_ + 192));                   \
    P##4 = __builtin_nontemporal_load(lg4 + CLK(b_ + 256));                   \
    P##5 = __builtin_nontemporal_load(lg4 + CLK(b_ + 320));                   \
    if (lane < 16) P##6 = __builtin_nontemporal_load(lg4 + CLK(b_ + 384));    \
    if (q == 0) { const int rr_ = (cc) * CROWS + r;                           \
                  lab##P = __builtin_nontemporal_load(                        \
                               labels + (rr_ < N ? rr_ : N - 1)); }           \
} while (0)
// each ISSUE = exactly 8 vmem loads per wave (6 full + 2 exec-masked)
// NOTE: lab##P with P=sA pastes to labsA (declared above).

#define DSW(P, b) do {                                                        \
    nat_f4* d_ = (nat_f4*)&s_tile[wv][b][lane];                               \
    d_[0]   = P##0; d_[64]  = P##1; d_[128] = P##2;                           \
    d_[192] = P##3; d_[256] = P##4; d_[320] = P##5;                           \
    if (lane < 16) d_[384] = P##6;                                            \
} while (0)

#define VMW8  asm volatile("s_waitcnt vmcnt(8)" ::: "memory")
#define VMW0  asm volatile("s_waitcnt vmcnt(0)" ::: "memory")
#define LGKM0 asm volatile("s_waitcnt lgkmcnt(0)" ::: "memory")
#define SBR   __builtin_amdgcn_sched_barrier(0)

    int  c     = blockIdx.x * WPB + wv;   // this wave's first chunk
    bool vCur  = (c < nChunks);
    bool vNext = (c + stride < nChunks);
    int  cur   = 0;

    if (vCur)  ISSUE(sA, c);
    if (vNext) ISSUE(sB, c + stride);
    if (vCur) {
        if (vNext) VMW8; else VMW0;       // set A landed; B stays in flight
        SBR;
        DSW(sA, 0);
        LGKM0; SBR;                       // same-wave RAW: writes complete before reads
    }

    if (vCur) for (;;) {
        {   // phase A: compute chunk c (set A -> buf cur); set B in flight
            const int  cn2 = c + 2 * stride;
            const bool v2  = cn2 < nChunks;
            const int  labCur = labsA;            // copy before re-issue clobbers
            if (v2) ISSUE(sA, cn2);
            compute_chunk(&s_tile[wv][cur][0], r, q, (long long)c * CROWS,
                          labCur, scale, N, s_cnt, s_conf, s_acc);
            if (vNext) {
                if (v2) VMW8; else VMW0;          // set B landed
                SBR;
                DSW(sB, cur ^ 1);
                LGKM0; SBR;
            }
            vCur = vNext; vNext = v2; c += stride; cur ^= 1;
            if (!vCur) break;
        }
        {   // phase B: roles swapped
            const int  cn2 = c + 2 * stride;
            const bool v2  = cn2 < nChunks;
            const int  labCur = labsB;
            if (v2) ISSUE(sB, cn2);
            compute_chunk(&s_tile[wv][cur][0], r, q, (long long)c * CROWS,
                          labCur, scale, N, s_cnt, s_conf, s_acc);
            if (vNext) {
                if (v2) VMW8; else VMW0;          // set A landed
                SBR;
                DSW(sA, cur ^ 1);
                LGKM0; SBR;
            }
            vCur = vNext; vNext = v2; c += stride; cur ^= 1;
            if (!vCur) break;
        }
    }

    VMW0;                 // no loads outstanding at endpgm
    __syncthreads();      // all histogram atomics done before flush
    if (tid < NBINS) {
        atomicAdd(&gbins[tid],             s_cnt[tid]);
        atomicAdd(&gbins[NBINS + tid],     s_conf[tid]);
        atomicAdd(&gbins[2 * NBINS + tid], s_acc[tid]);
    }
#undef CLK
#undef ISSUE
#undef DSW
#undef VMW8
#undef VMW0
#undef LGKM0
#undef SBR
}

__global__ void ece_final(const float* __restrict__ gbins,
                          float* __restrict__ out, int N) {
    if (threadIdx.x == 0 && blockIdx.x == 0) {
        float ece = 0.f;
        for (int b = 0; b < NBINS; ++b) {
            const float c = gbins[b];
            if (c > 0.f) {
                const float avg_conf = gbins[NBINS + b] / c;
                const float avg_acc  = gbins[2 * NBINS + b] / c;
                ece += fabsf(avg_conf - avg_acc) * (c / (float)N);
            }
        }
        out[0] = ece;
    }
}

extern "C" void kernel_launch(void* const* d_in, const int* in_sizes, int n_in,
                              void* d_out, int out_size, void* d_ws, size_t ws_size,
                              hipStream_t stream) {
    const float* logits = (const float*)d_in[0];
    const int*   labels = (const int*)d_in[1];
    const int*   t_opt  = (const int*)d_in[2];
    float* out   = (float*)d_out;
    float* gbins = (float*)d_ws;

    const int N = in_sizes[1];               // 1,000,000 rows (C fixed at 100)

    hipMemsetAsync(gbins, 0, 3 * NBINS * sizeof(float), stream);

    const int nChunks = (N + CROWS - 1) / CROWS;
    int blocks = (nChunks + WPB - 1) / WPB;
    if (blocks > 768) blocks = 768;          // 3 blocks/CU x 256 CU, 12 free-running waves/CU
    ece_main<<<blocks, BLOCK, 0, stream>>>(logits, labels, t_opt, gbins, N);
    ece_final<<<1, 64, 0, stream>>>(gbins, out, N);
}